// Round 8
// baseline (801.977 us; speedup 1.0000x reference)
//
#include <hip/hip_runtime.h>
#include <math.h>

// Problem constants
constexpr int CVOC = 100;
constexpr int NCLS = 18;
constexpr int EE   = 512;   // word emb
constexpr int HHm  = 512;   // main GRU hidden
constexpr int CEc  = 128;   // char emb
constexpr int CHc  = 256;   // char GRU hidden
constexpr int BB   = 64;
constexpr int TT   = 64;
constexpr int CCh  = 16;    // chars per word
constexpr int NTOK = BB*TT;       // 4096
constexpr int G3C  = 3*CHc;       // 768
constexpr int G3H  = 3*HHm;       // 1536
constexpr int KIN  = EE + CHc;    // 768

typedef __attribute__((ext_vector_type(8))) short bf16x8;
typedef __attribute__((ext_vector_type(4))) float f32x4;

__device__ __forceinline__ float sigmoidf_(float x){ return 1.0f/(1.0f + __expf(-x)); }
__device__ __forceinline__ float tanhf_(float x){ return 1.0f - 2.0f/(__expf(2.0f*x) + 1.0f); }
__device__ __forceinline__ unsigned short f2bf(float x){
  unsigned int u = __float_as_uint(x);
  unsigned int r = (u + 0x7FFFu + ((u>>16)&1u)) >> 16;
  return (unsigned short)r;
}

// ---------------------------------------------------------------------------
// K1: char input-projection table U2[c][g] (f32, biases folded; +bhh for r,z)
__global__ void k_uchar(const float* __restrict__ cemb, const float* __restrict__ wih,
                        const float* __restrict__ bih, const float* __restrict__ bhh,
                        float* __restrict__ U2){
  const int c = blockIdx.x;
  const int g = threadIdx.x;
  const float* a = cemb + (size_t)c*CEc;
  const float* w = wih  + (size_t)g*CEc;
  float s = 0.f;
  for(int k=0;k<CEc;k++) s = fmaf(a[k], w[k], s);
  s += bih[g];
  if(g < 2*CHc) s += bhh[g];
  U2[(size_t)c*G3C + g] = s;
}

// ---------------------------------------------------------------------------
// generic transpose: in[R][C] -> out[C][R]
__global__ void k_transpose(const float* __restrict__ in, float* __restrict__ out,
                            int R, int C){
  int idx = blockIdx.x*blockDim.x + threadIdx.x;
  if(idx >= R*C) return;
  int k = idx / R;
  int j = idx % R;
  out[idx] = in[(size_t)j*C + k];
}

// ---------------------------------------------------------------------------
// f32 -> bf16 (RNE)
__global__ void k_w2bf(const float* __restrict__ in, unsigned short* __restrict__ out,
                       int n){
  int i = blockIdx.x*256 + threadIdx.x;
  if(i < n) out[i] = f2bf(in[i]);
}

// ---------------------------------------------------------------------------
// K2 v4: char GRU, bf16 MFMA, 32 words/block (128 blocks), REGISTER epilogue.
// 256 thr = 4 waves; wave wv owns cols [wv*64,+64) of each gate.
// acc[gate][q][mt]: D tile (m-tile mt: words mt*16.., col wv*64+q*16+(l&15)).
// Thread-invariant ownership: words w=mt*16+lb*4+i, cols c=wv*64+q*16+la ->
// h f32 lives in 32 VGPRs across all 16 steps; LDS only carries bf16 h (A-frag).
// Fragment mappings identical to round-7-verified kernel.
__global__ __launch_bounds__(256) void k_chargru(
    const int* __restrict__ chars, const float* __restrict__ U2,
    const unsigned short* __restrict__ Wb, const float* __restrict__ bhh,
    float* __restrict__ char_h){
  __shared__ unsigned short hb[32][264];  // 16.9KB (stride 528B: 16B-aligned, 2-way banks)
  __shared__ int chs[32];
  const int tid  = threadIdx.x;
  const int lane = tid & 63;
  const int wv   = tid >> 6;        // 0..3
  const int la   = lane & 15;
  const int lb   = lane >> 4;       // 0..3
  const int w0   = blockIdx.x * 32;
  float bhn[4];
  #pragma unroll
  for(int q=0;q<4;q++) bhn[q] = bhh[2*CHc + wv*64 + q*16 + la];
  float hfr[2][4][4];               // [mt][i][q]
  #pragma unroll
  for(int mt=0;mt<2;mt++)
    #pragma unroll
    for(int i=0;i<4;i++)
      #pragma unroll
      for(int q=0;q<4;q++) hfr[mt][i][q]=0.f;
  for(int f=tid; f<32*264; f+=256) (&hb[0][0])[f] = 0;
  __syncthreads();

  for(int t=0;t<CCh;t++){
    if(tid<32) chs[tid] = chars[(size_t)(w0+tid)*CCh + t];
    // ---- MFMA: gh = h @ W^T, this wave's 12 (gate,q) tiles x 2 m-tiles ----
    f32x4 acc[3][4][2];
    #pragma unroll
    for(int g=0;g<3;g++)
      #pragma unroll
      for(int q=0;q<4;q++)
        #pragma unroll
        for(int mt=0;mt<2;mt++) acc[g][q][mt] = (f32x4){0.f,0.f,0.f,0.f};
    #pragma unroll
    for(int ks=0;ks<8;ks++){
      bf16x8 a0 = *reinterpret_cast<const bf16x8*>(&hb[la][ks*32 + lb*8]);
      bf16x8 a1 = *reinterpret_cast<const bf16x8*>(&hb[16+la][ks*32 + lb*8]);
      #pragma unroll
      for(int g=0;g<3;g++)
        #pragma unroll
        for(int q=0;q<4;q++){
          const int gcol = g*CHc + wv*64 + q*16 + la;
          bf16x8 bv = *reinterpret_cast<const bf16x8*>(&Wb[(size_t)gcol*CHc + ks*32 + lb*8]);
          acc[g][q][0] = __builtin_amdgcn_mfma_f32_16x16x32_bf16(a0, bv, acc[g][q][0], 0,0,0);
          acc[g][q][1] = __builtin_amdgcn_mfma_f32_16x16x32_bf16(a1, bv, acc[g][q][1], 0,0,0);
        }
    }
    __syncthreads();   // MFMA hb reads done; chs visible
    // ---- register epilogue ----
    #pragma unroll
    for(int mt=0;mt<2;mt++)
      #pragma unroll
      for(int i=0;i<4;i++){
        const int w = mt*16 + lb*4 + i;
        const float* u = U2 + (size_t)chs[w]*G3C;
        #pragma unroll
        for(int q=0;q<4;q++){
          const int c = wv*64 + q*16 + la;
          float r = sigmoidf_(u[c]         + acc[0][q][mt][i]);
          float z = sigmoidf_(u[CHc + c]   + acc[1][q][mt][i]);
          float n = tanhf_   (u[2*CHc + c] + r*(acc[2][q][mt][i] + bhn[q]));
          float hp = hfr[mt][i][q];
          float hn = (1.f - z)*n + z*hp;
          hfr[mt][i][q] = hn;
          hb[w][c] = f2bf(hn);
        }
      }
    __syncthreads();   // hb ready for next MFMA; chs consumed
  }
  #pragma unroll
  for(int mt=0;mt<2;mt++)
    #pragma unroll
    for(int i=0;i<4;i++){
      const int w = mt*16 + lb*4 + i;
      #pragma unroll
      for(int q=0;q<4;q++){
        const int c = wv*64 + q*16 + la;
        char_h[(size_t)(w0+w)*CHc + c] = hfr[mt][i][q];
      }
    }
}

// ---------------------------------------------------------------------------
// K3: gx GEMM, f32 (unchanged). gx[token][g], bias folded (+bhh for r,z).
__global__ __launch_bounds__(256) void k_gxmain(
    const int* __restrict__ x, const float* __restrict__ wemb,
    const float* __restrict__ chh, const float* __restrict__ WihT,
    const float* __restrict__ bih, const float* __restrict__ bhh,
    float* __restrict__ gx){
  __shared__ float As[128][20];
  __shared__ float Bs[16][100];
  __shared__ int xs[128];
  const int tid = threadIdx.x;
  const int rb = blockIdx.x * 128;
  const int nb = blockIdx.y * 96;
  if(tid < 128) xs[tid] = x[rb + tid];
  const int tr = tid >> 4, tc = tid & 15;
  float acc[8][6];
  #pragma unroll
  for(int i=0;i<8;i++)
    #pragma unroll
    for(int j=0;j<6;j++) acc[i][j]=0.f;
  __syncthreads();
  for(int kb=0; kb<KIN; kb+=16){
    #pragma unroll
    for(int i=0;i<2;i++){
      int idx = i*256 + tid;
      int m = idx & 127, kq = idx >> 7;
      int k = kb + kq*4;
      float4 v;
      if(k < EE) v = *reinterpret_cast<const float4*>(&wemb[(size_t)xs[m]*EE + k]);
      else       v = *reinterpret_cast<const float4*>(&chh[(size_t)(rb+m)*CHc + (k-EE)]);
      *reinterpret_cast<float4*>(&As[m][kq*4]) = v;
    }
    #pragma unroll
    for(int i=0;i<2;i++){
      int idx = i*256 + tid;
      if(idx < 384){
        int k = idx / 24, n4 = (idx % 24)*4;
        *reinterpret_cast<float4*>(&Bs[k][n4]) =
            *reinterpret_cast<const float4*>(&WihT[(size_t)(kb+k)*G3H + nb + n4]);
      }
    }
    __syncthreads();
    #pragma unroll
    for(int k=0;k<16;k++){
      float a[8];
      #pragma unroll
      for(int i=0;i<4;i++){ a[i]=As[tr*4+i][k]; a[4+i]=As[64+tr*4+i][k]; }
      float2 b0 = *reinterpret_cast<const float2*>(&Bs[k][tc*2]);
      float2 b1 = *reinterpret_cast<const float2*>(&Bs[k][32+tc*2]);
      float2 b2 = *reinterpret_cast<const float2*>(&Bs[k][64+tc*2]);
      float b[6] = {b0.x,b0.y,b1.x,b1.y,b2.x,b2.y};
      #pragma unroll
      for(int i=0;i<8;i++)
        #pragma unroll
        for(int j=0;j<6;j++)
          acc[i][j] = fmaf(a[i], b[j], acc[i][j]);
    }
    __syncthreads();
  }
  #pragma unroll
  for(int i=0;i<8;i++){
    int row = rb + ((i<4) ? tr*4+i : 64 + tr*4 + (i-4));
    #pragma unroll
    for(int j=0;j<6;j++){
      int g = nb + (j>>1)*32 + tc*2 + (j&1);
      float v = acc[i][j] + bih[g] + (g < 2*HHm ? bhh[g] : 0.f);
      gx[(size_t)row*G3H + g] = v;
    }
  }
}

// ---------------------------------------------------------------------------
// K4 v5: main GRU with TAG-PACKED h exchange (no flags, no exchange-drain).
// 256 blocks = (jb 32) x (bb 8); 512 thr; reg-stationary weights (as v4).
// h exchanged as u64 {hi=tag=t+1, lo=f32 h} in hx[2][64][512] ping-pong via
// RELAXED AGENT atomics. Consumer polls data words directly until tag==t.
// Depth-2 slot reuse is safe: a block reaches step t+2's store only after all
// peers' t+1 data exists, which implies every consumer finished staging t.
// Replay-safe: stale tags (prev replay end-state 63/64, or 0xAAAAAAAA poison)
// never equal the expected tag. outh (f32) written separately for k_cls.
__global__ __launch_bounds__(512) void k_grumain(
    const float* __restrict__ Whh, const float* __restrict__ gx,
    const float* __restrict__ bhh, float* __restrict__ outh,
    unsigned long long* __restrict__ hx){
  __shared__ float hsh[8][516];      // 16.5KB
  __shared__ float red[3][8][16][9]; // 13.8KB
  const int tid  = threadIdx.x;
  const int lane = tid & 63;
  const int kw   = tid >> 6;
  const int jp   = lane & 15;
  const int bq   = lane >> 4;
  const int jb   = blockIdx.x & 31;
  const int bb   = blockIdx.x >> 5;
  const int jglob = jb*16 + jp;
  const int kbase = kw*64 + bq*16;
  float4 wreg[3][4];
  #pragma unroll
  for(int g=0; g<3; g++)
    #pragma unroll
    for(int q=0; q<4; q++)
      wreg[g][q] = *reinterpret_cast<const float4*>(
          &Whh[((size_t)g*HHm + jglob)*HHm + kbase + q*4]);
  const int fb  = tid >> 4;
  const int fj  = tid & 15;
  const int fjg = jb*16 + fj;
  const int fbg = bb*8 + fb;
  const float fbhn = bhh[2*HHm + fjg];

  for(int t=0; t<TT; t++){
    float gxr=0.f, gxz=0.f, gxn=0.f;
    if(tid < 128){
      const size_t tok = (size_t)fbg*TT + t;
      gxr = gx[tok*G3H +           fjg];
      gxz = gx[tok*G3H + HHm +     fjg];
      gxn = gx[tok*G3H + 2*HHm +   fjg];
    }
    if(t > 0){
      // stage h_{t-1}: poll tagged words directly (tag == t)
      const unsigned int want = (unsigned int)t;
      const size_t sbase = (size_t)((t-1)&1)*BB*HHm;
      #pragma unroll
      for(int i=0;i<8;i++){
        int f = i*512 + tid;
        int b = f >> 9, k = f & 511;
        const unsigned long long* p = &hx[sbase + (size_t)(bb*8+b)*HHm + k];
        unsigned long long v = __hip_atomic_load(p, __ATOMIC_RELAXED, __HIP_MEMORY_SCOPE_AGENT);
        while((unsigned int)(v>>32) != want){
          __builtin_amdgcn_s_sleep(1);
          v = __hip_atomic_load(p, __ATOMIC_RELAXED, __HIP_MEMORY_SCOPE_AGENT);
        }
        hsh[b][k] = __uint_as_float((unsigned int)v);
      }
      __syncthreads();
      float aR[8], aZ[8], aN[8];
      #pragma unroll
      for(int b=0;b<8;b++){ aR[b]=0.f; aZ[b]=0.f; aN[b]=0.f; }
      #pragma unroll
      for(int b=0; b<8; b++){
        float4 h0 = *reinterpret_cast<const float4*>(&hsh[b][kbase+0]);
        float4 h1 = *reinterpret_cast<const float4*>(&hsh[b][kbase+4]);
        float4 h2 = *reinterpret_cast<const float4*>(&hsh[b][kbase+8]);
        float4 h3 = *reinterpret_cast<const float4*>(&hsh[b][kbase+12]);
        aR[b] = fmaf(h0.x,wreg[0][0].x, fmaf(h0.y,wreg[0][0].y, fmaf(h0.z,wreg[0][0].z, fmaf(h0.w,wreg[0][0].w, aR[b]))));
        aR[b] = fmaf(h1.x,wreg[0][1].x, fmaf(h1.y,wreg[0][1].y, fmaf(h1.z,wreg[0][1].z, fmaf(h1.w,wreg[0][1].w, aR[b]))));
        aR[b] = fmaf(h2.x,wreg[0][2].x, fmaf(h2.y,wreg[0][2].y, fmaf(h2.z,wreg[0][2].z, fmaf(h2.w,wreg[0][2].w, aR[b]))));
        aR[b] = fmaf(h3.x,wreg[0][3].x, fmaf(h3.y,wreg[0][3].y, fmaf(h3.z,wreg[0][3].z, fmaf(h3.w,wreg[0][3].w, aR[b]))));
        aZ[b] = fmaf(h0.x,wreg[1][0].x, fmaf(h0.y,wreg[1][0].y, fmaf(h0.z,wreg[1][0].z, fmaf(h0.w,wreg[1][0].w, aZ[b]))));
        aZ[b] = fmaf(h1.x,wreg[1][1].x, fmaf(h1.y,wreg[1][1].y, fmaf(h1.z,wreg[1][1].z, fmaf(h1.w,wreg[1][1].w, aZ[b]))));
        aZ[b] = fmaf(h2.x,wreg[1][2].x, fmaf(h2.y,wreg[1][2].y, fmaf(h2.z,wreg[1][2].z, fmaf(h2.w,wreg[1][2].w, aZ[b]))));
        aZ[b] = fmaf(h3.x,wreg[1][3].x, fmaf(h3.y,wreg[1][3].y, fmaf(h3.z,wreg[1][3].z, fmaf(h3.w,wreg[1][3].w, aZ[b]))));
        aN[b] = fmaf(h0.x,wreg[2][0].x, fmaf(h0.y,wreg[2][0].y, fmaf(h0.z,wreg[2][0].z, fmaf(h0.w,wreg[2][0].w, aN[b]))));
        aN[b] = fmaf(h1.x,wreg[2][1].x, fmaf(h1.y,wreg[2][1].y, fmaf(h1.z,wreg[2][1].z, fmaf(h1.w,wreg[2][1].w, aN[b]))));
        aN[b] = fmaf(h2.x,wreg[2][2].x, fmaf(h2.y,wreg[2][2].y, fmaf(h2.z,wreg[2][2].z, fmaf(h2.w,wreg[2][2].w, aN[b]))));
        aN[b] = fmaf(h3.x,wreg[2][3].x, fmaf(h3.y,wreg[2][3].y, fmaf(h3.z,wreg[2][3].z, fmaf(h3.w,wreg[2][3].w, aN[b]))));
      }
      #pragma unroll
      for(int b=0;b<8;b++){
        aR[b] += __shfl_xor(aR[b], 16, 64); aR[b] += __shfl_xor(aR[b], 32, 64);
        aZ[b] += __shfl_xor(aZ[b], 16, 64); aZ[b] += __shfl_xor(aZ[b], 32, 64);
        aN[b] += __shfl_xor(aN[b], 16, 64); aN[b] += __shfl_xor(aN[b], 32, 64);
      }
      #pragma unroll
      for(int i=0;i<2;i++){
        int b = bq*2 + i;
        red[0][b][jp][kw] = aR[b];
        red[1][b][jp][kw] = aZ[b];
        red[2][b][jp][kw] = aN[b];
      }
      __syncthreads();
    }
    if(tid < 128){
      float sR=0.f, sZ=0.f, sN=0.f, hold=0.f;
      if(t > 0){
        #pragma unroll
        for(int w=0; w<8; w++){
          sR += red[0][fb][fj][w];
          sZ += red[1][fb][fj][w];
          sN += red[2][fb][fj][w];
        }
        hold = hsh[fb][fjg];
      }
      float rg = sigmoidf_(gxr + sR);
      float zg = sigmoidf_(gxz + sZ);
      float ng = tanhf_   (gxn + rg*(sN + fbhn));
      float hnew = (1.f - zg)*ng + zg*hold;
      outh[((size_t)t*BB + fbg)*HHm + fjg] = hnew;   // f32 for k_cls
      unsigned long long pv = ((unsigned long long)(unsigned int)(t+1) << 32)
                              | (unsigned long long)__float_as_uint(hnew);
      __hip_atomic_store(&hx[(size_t)(t&1)*BB*HHm + (size_t)fbg*HHm + fjg], pv,
                         __ATOMIC_RELAXED, __HIP_MEMORY_SCOPE_AGENT);
    }
    __syncthreads();   // protect hsh/red before next iteration overwrites
  }
}

// ---------------------------------------------------------------------------
// K5: classifier. One block per time-step t; reads outh[t][b][j].
__global__ __launch_bounds__(256) void k_cls(
    const float* __restrict__ outh, const float* __restrict__ clsW,
    const float* __restrict__ clsb, float* __restrict__ out){
  __shared__ float wls[20*HHm];     // 40KB
  __shared__ float hch[64][129];    // 33KB
  const int tid = threadIdx.x;
  const int t = blockIdx.x;
  const int b = tid & 63;
  const int q = tid >> 6;
  const int c0 = q*5;
  for(int f = tid*4; f < 20*HHm; f += 1024){
    float4 v = make_float4(0.f,0.f,0.f,0.f);
    if(f < NCLS*HHm) v = *reinterpret_cast<const float4*>(&clsW[f]);
    *reinterpret_cast<float4*>(&wls[f]) = v;
  }
  float acc[5] = {0.f,0.f,0.f,0.f,0.f};
  for(int kc=0; kc<4; kc++){
    __syncthreads();
    for(int i=0;i<32;i++){
      int f = i*256 + tid;
      int b2 = f >> 7, kk = f & 127;
      hch[b2][kk] = outh[((size_t)t*BB + b2)*HHm + kc*128 + kk];
    }
    __syncthreads();
    for(int k=0;k<128;k++){
      float hv = hch[b][k];
      #pragma unroll
      for(int i=0;i<5;i++)
        acc[i] = fmaf(hv, wls[(size_t)(c0+i)*HHm + kc*128 + k], acc[i]);
    }
  }
  #pragma unroll
  for(int i=0;i<5;i++){
    int cls = c0 + i;
    if(cls < NCLS) out[((size_t)b*TT + t)*NCLS + cls] = acc[i] + clsb[cls];
  }
}

// ---------------------------------------------------------------------------
extern "C" void kernel_launch(void* const* d_in, const int* in_sizes, int n_in,
                              void* d_out, int out_size, void* d_ws, size_t ws_size,
                              hipStream_t stream){
  const int*   x     = (const int*)d_in[0];
  const int*   chars = (const int*)d_in[1];
  const float* wemb  = (const float*)d_in[2];
  const float* cemb  = (const float*)d_in[3];
  const float* cWih  = (const float*)d_in[4];
  const float* cWhh  = (const float*)d_in[5];
  const float* cbih  = (const float*)d_in[6];
  const float* cbhh  = (const float*)d_in[7];
  const float* gWih  = (const float*)d_in[8];
  const float* gWhh  = (const float*)d_in[9];
  const float* gbih  = (const float*)d_in[10];
  const float* gbhh  = (const float*)d_in[11];
  const float* clsW  = (const float*)d_in[12];
  const float* clsb  = (const float*)d_in[13];
  float* out = (float*)d_out;
  float* ws  = (float*)d_ws;

  // workspace layout (floats unless noted)
  float* U2    = ws;                   // 100*768    = 76800
  float* WihTm = U2 + 76800;           // 768*1536   = 1179648
  float* chh   = WihTm + 1179648;      // 4096*256   = 1048576
  float* gx    = chh + 1048576;        // 4096*1536  = 6291456   [token][g]
  float* outh  = gx + 6291456;         // 64*64*512  = 2097152   [t][b][j]
  unsigned long long* hx = (unsigned long long*)(outh + 2097152); // 2*64*512 u64
  unsigned short* Wb = (unsigned short*)(hx + 2*BB*HHm);          // 768*256 bf16

  k_uchar<<<CVOC, G3C, 0, stream>>>(cemb, cWih, cbih, cbhh, U2);
  k_w2bf<<<(G3C*CHc + 255)/256, 256, 0, stream>>>(cWhh, Wb, G3C*CHc);
  k_transpose<<<(G3H*KIN + 255)/256, 256, 0, stream>>>(gWih, WihTm, G3H, KIN);
  k_chargru<<<NTOK/32, 256, 0, stream>>>(chars, U2, Wb, cbhh, chh);
  k_gxmain<<<dim3(NTOK/128, G3H/96), 256, 0, stream>>>(x, wemb, chh, WihTm, gbih, gbhh, gx);
  k_grumain<<<256, 512, 0, stream>>>(gWhh, gx, gbhh, outh, hx);
  k_cls<<<TT, 256, 0, stream>>>(outh, clsW, clsb, out);
}

// Round 9
// 639.723 us; speedup vs baseline: 1.2536x; 1.2536x over previous
//
#include <hip/hip_runtime.h>
#include <math.h>

// Problem constants
constexpr int CVOC = 100;
constexpr int NCLS = 18;
constexpr int EE   = 512;   // word emb
constexpr int HHm  = 512;   // main GRU hidden
constexpr int CEc  = 128;   // char emb
constexpr int CHc  = 256;   // char GRU hidden
constexpr int BB   = 64;
constexpr int TT   = 64;
constexpr int CCh  = 16;    // chars per word
constexpr int NTOK = BB*TT;       // 4096
constexpr int G3C  = 3*CHc;       // 768
constexpr int G3H  = 3*HHm;       // 1536
constexpr int KIN  = EE + CHc;    // 768

typedef __attribute__((ext_vector_type(8))) short bf16x8;
typedef __attribute__((ext_vector_type(4))) float f32x4;

__device__ __forceinline__ float sigmoidf_(float x){ return 1.0f/(1.0f + __expf(-x)); }
__device__ __forceinline__ float tanhf_(float x){ return 1.0f - 2.0f/(__expf(2.0f*x) + 1.0f); }
__device__ __forceinline__ unsigned short f2bf(float x){
  unsigned int u = __float_as_uint(x);
  unsigned int r = (u + 0x7FFFu + ((u>>16)&1u)) >> 16;
  return (unsigned short)r;
}

// ---------------------------------------------------------------------------
// K1: char input-projection table U2[c][g] (f32, biases folded; +bhh for r,z)
__global__ void k_uchar(const float* __restrict__ cemb, const float* __restrict__ wih,
                        const float* __restrict__ bih, const float* __restrict__ bhh,
                        float* __restrict__ U2){
  const int c = blockIdx.x;
  const int g = threadIdx.x;
  const float* a = cemb + (size_t)c*CEc;
  const float* w = wih  + (size_t)g*CEc;
  float s = 0.f;
  for(int k=0;k<CEc;k++) s = fmaf(a[k], w[k], s);
  s += bih[g];
  if(g < 2*CHc) s += bhh[g];
  U2[(size_t)c*G3C + g] = s;
}

// ---------------------------------------------------------------------------
// generic transpose: in[R][C] -> out[C][R]
__global__ void k_transpose(const float* __restrict__ in, float* __restrict__ out,
                            int R, int C){
  int idx = blockIdx.x*blockDim.x + threadIdx.x;
  if(idx >= R*C) return;
  int k = idx / R;
  int j = idx % R;
  out[idx] = in[(size_t)j*C + k];
}

// ---------------------------------------------------------------------------
// f32 -> bf16 (RNE)
__global__ void k_w2bf(const float* __restrict__ in, unsigned short* __restrict__ out,
                       int n){
  int i = blockIdx.x*256 + threadIdx.x;
  if(i < n) out[i] = f2bf(in[i]);
}

// ---------------------------------------------------------------------------
// K2 v5: char GRU, bf16 MFMA, FULLY REGISTER-RESIDENT weights.
// 256 blocks x 512 thr (8 waves), 16 words/block (1 block/CU).
// Wave wv owns cols [wv*32,+32) of EACH of the 3 gates -> 6 MFMA tiles:
//   tile (g,q): gcol = g*256 + wv*32 + q*16 + la
// B-frags wreg[3][2][8] (48 x bf16x8 = 192 VGPR) loaded ONCE before the t-loop
// -> per-step weight traffic = ZERO. A-frags from LDS hb (8 reads/step).
// U2 gate rows for step t+1 cooperatively prefetched (coalesced) into
// double-buffered LDS ux during step t's epilogue -> gather latency hidden.
// Per step: [MFMA 48] barrier [epilogue(reg) || gather(t+1)] barrier.
// Math identical to round-8 kernel (f32 gates, bf16 h operands).
__global__ __launch_bounds__(512, 2) void k_chargru(
    const int* __restrict__ chars, const float* __restrict__ U2,
    const unsigned short* __restrict__ Wb, const float* __restrict__ bhh,
    float* __restrict__ char_h){
  __shared__ unsigned short hb[16][264];   // 8.4KB bf16 h
  __shared__ float ux[2][16][772];         // 98.7KB gathered U2 rows (dbuf)
  const int tid  = threadIdx.x;
  const int lane = tid & 63;
  const int wv   = tid >> 6;        // 0..7
  const int la   = lane & 15;
  const int lb   = lane >> 4;       // 0..3
  const int w0   = blockIdx.x * 16;
  // ---- one-time: all 6 B-tiles x 8 k-steps into registers ----
  bf16x8 wreg[3][2][8];
  #pragma unroll
  for(int g=0; g<3; g++)
    #pragma unroll
    for(int q=0; q<2; q++){
      const int gcol = g*CHc + wv*32 + q*16 + la;
      #pragma unroll
      for(int ks=0; ks<8; ks++)
        wreg[g][q][ks] = *reinterpret_cast<const bf16x8*>(
            &Wb[(size_t)gcol*CHc + ks*32 + lb*8]);
    }
  float bhn[2];
  #pragma unroll
  for(int q=0; q<2; q++) bhn[q] = bhh[2*CHc + wv*32 + q*16 + la];
  float hfr[4][2];                  // h f32: word lb*4+i, col wv*32+q*16+la
  #pragma unroll
  for(int i=0;i<4;i++){ hfr[i][0]=0.f; hfr[i][1]=0.f; }
  for(int f=tid; f<16*264; f+=512) (&hb[0][0])[f] = 0;
  // prologue: gather ux[0] for t=0
  #pragma unroll
  for(int i=0;i<6;i++){
    int idx = i*512 + tid;          // 0..3071
    int w = idx / 192;
    int c4 = idx - w*192;
    int ch = chars[(size_t)(w0+w)*CCh + 0];
    *reinterpret_cast<float4*>(&ux[0][w][c4*4]) =
        *reinterpret_cast<const float4*>(&U2[(size_t)ch*G3C + c4*4]);
  }
  __syncthreads();

  for(int t=0; t<CCh; t++){
    // ---- MFMA phase: 48 reg-MFMAs, A from LDS ----
    f32x4 acc[3][2];
    #pragma unroll
    for(int g=0;g<3;g++){ acc[g][0]=(f32x4){0.f,0.f,0.f,0.f}; acc[g][1]=(f32x4){0.f,0.f,0.f,0.f}; }
    #pragma unroll
    for(int ks=0; ks<8; ks++){
      bf16x8 a = *reinterpret_cast<const bf16x8*>(&hb[la][ks*32 + lb*8]);
      #pragma unroll
      for(int g=0;g<3;g++)
        #pragma unroll
        for(int q=0;q<2;q++)
          acc[g][q] = __builtin_amdgcn_mfma_f32_16x16x32_bf16(a, wreg[g][q][ks], acc[g][q], 0,0,0);
    }
    __syncthreads();   // hb reads done; ux[t&1] (gathered last iter) visible
    // ---- gather ux for t+1 (issued first so L2 latency hides under epilogue) ----
    if(t < CCh-1){
      const int buf = (t+1)&1;
      #pragma unroll
      for(int i=0;i<6;i++){
        int idx = i*512 + tid;
        int w = idx / 192;
        int c4 = idx - w*192;
        int ch = chars[(size_t)(w0+w)*CCh + (t+1)];
        *reinterpret_cast<float4*>(&ux[buf][w][c4*4]) =
            *reinterpret_cast<const float4*>(&U2[(size_t)ch*G3C + c4*4]);
      }
    }
    // ---- register epilogue (reads ux[t&1] from LDS) ----
    {
      const float* uxt = &ux[t&1][0][0];
      #pragma unroll
      for(int i=0;i<4;i++){
        const int w = lb*4 + i;
        const float* u = uxt + (size_t)w*772;
        #pragma unroll
        for(int q=0;q<2;q++){
          const int c = wv*32 + q*16 + la;
          float r = sigmoidf_(u[c]         + acc[0][q][i]);
          float z = sigmoidf_(u[CHc + c]   + acc[1][q][i]);
          float n = tanhf_   (u[2*CHc + c] + r*(acc[2][q][i] + bhn[q]));
          float hn = (1.f - z)*n + z*hfr[i][q];
          hfr[i][q] = hn;
          hb[w][c] = f2bf(hn);
        }
      }
    }
    __syncthreads();   // hb + ux[t+1] ready for next iteration
  }
  // ---- writeout ----
  #pragma unroll
  for(int i=0;i<4;i++){
    const int w = lb*4 + i;
    #pragma unroll
    for(int q=0;q<2;q++){
      const int c = wv*32 + q*16 + la;
      char_h[(size_t)(w0+w)*CHc + c] = hfr[i][q];
    }
  }
}

// ---------------------------------------------------------------------------
// K3: gx GEMM, f32 (unchanged). gx[token][g], bias folded (+bhh for r,z).
__global__ __launch_bounds__(256) void k_gxmain(
    const int* __restrict__ x, const float* __restrict__ wemb,
    const float* __restrict__ chh, const float* __restrict__ WihT,
    const float* __restrict__ bih, const float* __restrict__ bhh,
    float* __restrict__ gx){
  __shared__ float As[128][20];
  __shared__ float Bs[16][100];
  __shared__ int xs[128];
  const int tid = threadIdx.x;
  const int rb = blockIdx.x * 128;
  const int nb = blockIdx.y * 96;
  if(tid < 128) xs[tid] = x[rb + tid];
  const int tr = tid >> 4, tc = tid & 15;
  float acc[8][6];
  #pragma unroll
  for(int i=0;i<8;i++)
    #pragma unroll
    for(int j=0;j<6;j++) acc[i][j]=0.f;
  __syncthreads();
  for(int kb=0; kb<KIN; kb+=16){
    #pragma unroll
    for(int i=0;i<2;i++){
      int idx = i*256 + tid;
      int m = idx & 127, kq = idx >> 7;
      int k = kb + kq*4;
      float4 v;
      if(k < EE) v = *reinterpret_cast<const float4*>(&wemb[(size_t)xs[m]*EE + k]);
      else       v = *reinterpret_cast<const float4*>(&chh[(size_t)(rb+m)*CHc + (k-EE)]);
      *reinterpret_cast<float4*>(&As[m][kq*4]) = v;
    }
    #pragma unroll
    for(int i=0;i<2;i++){
      int idx = i*256 + tid;
      if(idx < 384){
        int k = idx / 24, n4 = (idx % 24)*4;
        *reinterpret_cast<float4*>(&Bs[k][n4]) =
            *reinterpret_cast<const float4*>(&WihT[(size_t)(kb+k)*G3H + nb + n4]);
      }
    }
    __syncthreads();
    #pragma unroll
    for(int k=0;k<16;k++){
      float a[8];
      #pragma unroll
      for(int i=0;i<4;i++){ a[i]=As[tr*4+i][k]; a[4+i]=As[64+tr*4+i][k]; }
      float2 b0 = *reinterpret_cast<const float2*>(&Bs[k][tc*2]);
      float2 b1 = *reinterpret_cast<const float2*>(&Bs[k][32+tc*2]);
      float2 b2 = *reinterpret_cast<const float2*>(&Bs[k][64+tc*2]);
      float b[6] = {b0.x,b0.y,b1.x,b1.y,b2.x,b2.y};
      #pragma unroll
      for(int i=0;i<8;i++)
        #pragma unroll
        for(int j=0;j<6;j++)
          acc[i][j] = fmaf(a[i], b[j], acc[i][j]);
    }
    __syncthreads();
  }
  #pragma unroll
  for(int i=0;i<8;i++){
    int row = rb + ((i<4) ? tr*4+i : 64 + tr*4 + (i-4));
    #pragma unroll
    for(int j=0;j<6;j++){
      int g = nb + (j>>1)*32 + tc*2 + (j&1);
      float v = acc[i][j] + bih[g] + (g < 2*HHm ? bhh[g] : 0.f);
      gx[(size_t)row*G3H + g] = v;
    }
  }
}

// ---------------------------------------------------------------------------
// K4 v5: main GRU with TAG-PACKED h exchange (unchanged from round 8; ~366us).
__global__ __launch_bounds__(512) void k_grumain(
    const float* __restrict__ Whh, const float* __restrict__ gx,
    const float* __restrict__ bhh, float* __restrict__ outh,
    unsigned long long* __restrict__ hx){
  __shared__ float hsh[8][516];      // 16.5KB
  __shared__ float red[3][8][16][9]; // 13.8KB
  const int tid  = threadIdx.x;
  const int lane = tid & 63;
  const int kw   = tid >> 6;
  const int jp   = lane & 15;
  const int bq   = lane >> 4;
  const int jb   = blockIdx.x & 31;
  const int bb   = blockIdx.x >> 5;
  const int jglob = jb*16 + jp;
  const int kbase = kw*64 + bq*16;
  float4 wreg[3][4];
  #pragma unroll
  for(int g=0; g<3; g++)
    #pragma unroll
    for(int q=0; q<4; q++)
      wreg[g][q] = *reinterpret_cast<const float4*>(
          &Whh[((size_t)g*HHm + jglob)*HHm + kbase + q*4]);
  const int fb  = tid >> 4;
  const int fj  = tid & 15;
  const int fjg = jb*16 + fj;
  const int fbg = bb*8 + fb;
  const float fbhn = bhh[2*HHm + fjg];

  for(int t=0; t<TT; t++){
    float gxr=0.f, gxz=0.f, gxn=0.f;
    if(tid < 128){
      const size_t tok = (size_t)fbg*TT + t;
      gxr = gx[tok*G3H +           fjg];
      gxz = gx[tok*G3H + HHm +     fjg];
      gxn = gx[tok*G3H + 2*HHm +   fjg];
    }
    if(t > 0){
      const unsigned int want = (unsigned int)t;
      const size_t sbase = (size_t)((t-1)&1)*BB*HHm;
      #pragma unroll
      for(int i=0;i<8;i++){
        int f = i*512 + tid;
        int b = f >> 9, k = f & 511;
        const unsigned long long* p = &hx[sbase + (size_t)(bb*8+b)*HHm + k];
        unsigned long long v = __hip_atomic_load(p, __ATOMIC_RELAXED, __HIP_MEMORY_SCOPE_AGENT);
        while((unsigned int)(v>>32) != want){
          __builtin_amdgcn_s_sleep(1);
          v = __hip_atomic_load(p, __ATOMIC_RELAXED, __HIP_MEMORY_SCOPE_AGENT);
        }
        hsh[b][k] = __uint_as_float((unsigned int)v);
      }
      __syncthreads();
      float aR[8], aZ[8], aN[8];
      #pragma unroll
      for(int b=0;b<8;b++){ aR[b]=0.f; aZ[b]=0.f; aN[b]=0.f; }
      #pragma unroll
      for(int b=0; b<8; b++){
        float4 h0 = *reinterpret_cast<const float4*>(&hsh[b][kbase+0]);
        float4 h1 = *reinterpret_cast<const float4*>(&hsh[b][kbase+4]);
        float4 h2 = *reinterpret_cast<const float4*>(&hsh[b][kbase+8]);
        float4 h3 = *reinterpret_cast<const float4*>(&hsh[b][kbase+12]);
        aR[b] = fmaf(h0.x,wreg[0][0].x, fmaf(h0.y,wreg[0][0].y, fmaf(h0.z,wreg[0][0].z, fmaf(h0.w,wreg[0][0].w, aR[b]))));
        aR[b] = fmaf(h1.x,wreg[0][1].x, fmaf(h1.y,wreg[0][1].y, fmaf(h1.z,wreg[0][1].z, fmaf(h1.w,wreg[0][1].w, aR[b]))));
        aR[b] = fmaf(h2.x,wreg[0][2].x, fmaf(h2.y,wreg[0][2].y, fmaf(h2.z,wreg[0][2].z, fmaf(h2.w,wreg[0][2].w, aR[b]))));
        aR[b] = fmaf(h3.x,wreg[0][3].x, fmaf(h3.y,wreg[0][3].y, fmaf(h3.z,wreg[0][3].z, fmaf(h3.w,wreg[0][3].w, aR[b]))));
        aZ[b] = fmaf(h0.x,wreg[1][0].x, fmaf(h0.y,wreg[1][0].y, fmaf(h0.z,wreg[1][0].z, fmaf(h0.w,wreg[1][0].w, aZ[b]))));
        aZ[b] = fmaf(h1.x,wreg[1][1].x, fmaf(h1.y,wreg[1][1].y, fmaf(h1.z,wreg[1][1].z, fmaf(h1.w,wreg[1][1].w, aZ[b]))));
        aZ[b] = fmaf(h2.x,wreg[1][2].x, fmaf(h2.y,wreg[1][2].y, fmaf(h2.z,wreg[1][2].z, fmaf(h2.w,wreg[1][2].w, aZ[b]))));
        aZ[b] = fmaf(h3.x,wreg[1][3].x, fmaf(h3.y,wreg[1][3].y, fmaf(h3.z,wreg[1][3].z, fmaf(h3.w,wreg[1][3].w, aZ[b]))));
        aN[b] = fmaf(h0.x,wreg[2][0].x, fmaf(h0.y,wreg[2][0].y, fmaf(h0.z,wreg[2][0].z, fmaf(h0.w,wreg[2][0].w, aN[b]))));
        aN[b] = fmaf(h1.x,wreg[2][1].x, fmaf(h1.y,wreg[2][1].y, fmaf(h1.z,wreg[2][1].z, fmaf(h1.w,wreg[2][1].w, aN[b]))));
        aN[b] = fmaf(h2.x,wreg[2][2].x, fmaf(h2.y,wreg[2][2].y, fmaf(h2.z,wreg[2][2].z, fmaf(h2.w,wreg[2][2].w, aN[b]))));
        aN[b] = fmaf(h3.x,wreg[2][3].x, fmaf(h3.y,wreg[2][3].y, fmaf(h3.z,wreg[2][3].z, fmaf(h3.w,wreg[2][3].w, aN[b]))));
      }
      #pragma unroll
      for(int b=0;b<8;b++){
        aR[b] += __shfl_xor(aR[b], 16, 64); aR[b] += __shfl_xor(aR[b], 32, 64);
        aZ[b] += __shfl_xor(aZ[b], 16, 64); aZ[b] += __shfl_xor(aZ[b], 32, 64);
        aN[b] += __shfl_xor(aN[b], 16, 64); aN[b] += __shfl_xor(aN[b], 32, 64);
      }
      #pragma unroll
      for(int i=0;i<2;i++){
        int b = bq*2 + i;
        red[0][b][jp][kw] = aR[b];
        red[1][b][jp][kw] = aZ[b];
        red[2][b][jp][kw] = aN[b];
      }
      __syncthreads();
    }
    if(tid < 128){
      float sR=0.f, sZ=0.f, sN=0.f, hold=0.f;
      if(t > 0){
        #pragma unroll
        for(int w=0; w<8; w++){
          sR += red[0][fb][fj][w];
          sZ += red[1][fb][fj][w];
          sN += red[2][fb][fj][w];
        }
        hold = hsh[fb][fjg];
      }
      float rg = sigmoidf_(gxr + sR);
      float zg = sigmoidf_(gxz + sZ);
      float ng = tanhf_   (gxn + rg*(sN + fbhn));
      float hnew = (1.f - zg)*ng + zg*hold;
      outh[((size_t)t*BB + fbg)*HHm + fjg] = hnew;   // f32 for k_cls
      unsigned long long pv = ((unsigned long long)(unsigned int)(t+1) << 32)
                              | (unsigned long long)__float_as_uint(hnew);
      __hip_atomic_store(&hx[(size_t)(t&1)*BB*HHm + (size_t)fbg*HHm + fjg], pv,
                         __ATOMIC_RELAXED, __HIP_MEMORY_SCOPE_AGENT);
    }
    __syncthreads();
  }
}

// ---------------------------------------------------------------------------
// K5: classifier. One block per time-step t; reads outh[t][b][j].
__global__ __launch_bounds__(256) void k_cls(
    const float* __restrict__ outh, const float* __restrict__ clsW,
    const float* __restrict__ clsb, float* __restrict__ out){
  __shared__ float wls[20*HHm];     // 40KB
  __shared__ float hch[64][129];    // 33KB
  const int tid = threadIdx.x;
  const int t = blockIdx.x;
  const int b = tid & 63;
  const int q = tid >> 6;
  const int c0 = q*5;
  for(int f = tid*4; f < 20*HHm; f += 1024){
    float4 v = make_float4(0.f,0.f,0.f,0.f);
    if(f < NCLS*HHm) v = *reinterpret_cast<const float4*>(&clsW[f]);
    *reinterpret_cast<float4*>(&wls[f]) = v;
  }
  float acc[5] = {0.f,0.f,0.f,0.f,0.f};
  for(int kc=0; kc<4; kc++){
    __syncthreads();
    for(int i=0;i<32;i++){
      int f = i*256 + tid;
      int b2 = f >> 7, kk = f & 127;
      hch[b2][kk] = outh[((size_t)t*BB + b2)*HHm + kc*128 + kk];
    }
    __syncthreads();
    for(int k=0;k<128;k++){
      float hv = hch[b][k];
      #pragma unroll
      for(int i=0;i<5;i++)
        acc[i] = fmaf(hv, wls[(size_t)(c0+i)*HHm + kc*128 + k], acc[i]);
    }
  }
  #pragma unroll
  for(int i=0;i<5;i++){
    int cls = c0 + i;
    if(cls < NCLS) out[((size_t)b*TT + t)*NCLS + cls] = acc[i] + clsb[cls];
  }
}

// ---------------------------------------------------------------------------
extern "C" void kernel_launch(void* const* d_in, const int* in_sizes, int n_in,
                              void* d_out, int out_size, void* d_ws, size_t ws_size,
                              hipStream_t stream){
  const int*   x     = (const int*)d_in[0];
  const int*   chars = (const int*)d_in[1];
  const float* wemb  = (const float*)d_in[2];
  const float* cemb  = (const float*)d_in[3];
  const float* cWih  = (const float*)d_in[4];
  const float* cWhh  = (const float*)d_in[5];
  const float* cbih  = (const float*)d_in[6];
  const float* cbhh  = (const float*)d_in[7];
  const float* gWih  = (const float*)d_in[8];
  const float* gWhh  = (const float*)d_in[9];
  const float* gbih  = (const float*)d_in[10];
  const float* gbhh  = (const float*)d_in[11];
  const float* clsW  = (const float*)d_in[12];
  const float* clsb  = (const float*)d_in[13];
  float* out = (float*)d_out;
  float* ws  = (float*)d_ws;

  // workspace layout (floats unless noted)
  float* U2    = ws;                   // 100*768    = 76800
  float* WihTm = U2 + 76800;           // 768*1536   = 1179648
  float* chh   = WihTm + 1179648;      // 4096*256   = 1048576
  float* gx    = chh + 1048576;        // 4096*1536  = 6291456   [token][g]
  float* outh  = gx + 6291456;         // 64*64*512  = 2097152   [t][b][j]
  unsigned long long* hx = (unsigned long long*)(outh + 2097152); // 2*64*512 u64
  unsigned short* Wb = (unsigned short*)(hx + 2*BB*HHm);          // 768*256 bf16

  k_uchar<<<CVOC, G3C, 0, stream>>>(cemb, cWih, cbih, cbhh, U2);
  k_w2bf<<<(G3C*CHc + 255)/256, 256, 0, stream>>>(cWhh, Wb, G3C*CHc);
  k_transpose<<<(G3H*KIN + 255)/256, 256, 0, stream>>>(gWih, WihTm, G3H, KIN);
  k_chargru<<<NTOK/16, 512, 0, stream>>>(chars, U2, Wb, cbhh, chh);
  k_gxmain<<<dim3(NTOK/128, G3H/96), 256, 0, stream>>>(x, wemb, chh, WihTm, gbih, gbhh, gx);
  k_grumain<<<256, 512, 0, stream>>>(gWhh, gx, gbhh, outh, hx);
  k_cls<<<TT, 256, 0, stream>>>(outh, clsW, clsb, out);
}